// Round 8
// baseline (96.516 us; speedup 1.0000x reference)
//
#include <hip/hip_runtime.h>

#define MAX_SPIKE 100000.0f

constexpr int BATCH  = 128;
constexpr int NIN    = 1024;
constexpr int MOUT   = 512;
constexpr int NWAVE  = 8;             // scan: n-segments per block
constexpr int SEGLEN = NIN / NWAVE;   // 128
constexpr int CPB    = 64;            // columns per scan block (one per lane)
constexpr int CH     = 8;             // scan prefetch chunk
constexpr int SCH    = 32;            // snapshot prefetch chunk
constexpr int ST     = 512;           // sort threads (8 waves)
constexpr int TOTCOL = BATCH * MOUT;  // 65536

typedef unsigned long long u64;

// ---------------- kernel 1: per-row stable argsort (hybrid bitonic) --------
// Emits packed pairs: pair[n] = (ro_bytes << 32) | float_bits(xs), where
// ro_bytes = sorted_index * MOUT * 4 (byte offset of a weight row).
__global__ __launch_bounds__(ST) void snn_sort_kernel(const float* __restrict__ x,
                                                      u64* __restrict__ pair_g) {
    __shared__ u64 keys[NIN];
    const int tid = threadIdx.x;
    const int b   = blockIdx.x;
    const int wv  = tid >> 6;
    const int l   = tid & 63;
    const int i0  = wv * 128 + l;     // bit6 == 0 always
    const int i1  = i0 + 64;

    // key = (float_bits << 32) | index: x >= 0 so uint order == float order;
    // index low bits make keys distinct -> deterministic == stable argsort.
    u64 e0 = ((u64)__float_as_uint(x[b * NIN + i0]) << 32) | (unsigned)i0;
    u64 e1 = ((u64)__float_as_uint(x[b * NIN + i1]) << 32) | (unsigned)i1;

    auto CE_SHFL = [&](u64& e, int idx, int k, int j) {
        u64 p = __shfl_xor(e, j, 64);
        bool lower   = ((l & j) == 0);
        bool asc     = ((idx & k) == 0);
        bool takeMin = (lower == asc);
        bool pLess   = (p < e);
        e = (pLess == takeMin) ? p : e;
    };
    auto CE_J64 = [&](int k) {
        bool asc = ((i0 & k) == 0);
        bool sw  = asc ? (e0 > e1) : (e0 < e1);
        if (sw) { u64 t = e0; e0 = e1; e1 = t; }
    };

    for (int k = 2; k <= 64; k <<= 1)
        for (int j = k >> 1; j >= 1; j >>= 1) { CE_SHFL(e0, i0, k, j); CE_SHFL(e1, i1, k, j); }
    CE_J64(128);
    for (int j = 32; j >= 1; j >>= 1) { CE_SHFL(e0, i0, 128, j); CE_SHFL(e1, i1, 128, j); }

    for (int k = 256; k <= NIN; k <<= 1) {
        keys[i0] = e0; keys[i1] = e1;
        __syncthreads();
        for (int j = k >> 1; j >= 128; j >>= 1) {
            int idx  = ((tid & ~(j - 1)) << 1) | (tid & (j - 1));
            int part = idx | j;
            u64 a = keys[idx], c = keys[part];
            bool asc = ((idx & k) == 0);
            if (asc ? (a > c) : (a < c)) { keys[idx] = c; keys[part] = a; }
            __syncthreads();
        }
        e0 = keys[i0]; e1 = keys[i1];
        CE_J64(k);
        for (int j = 32; j >= 1; j >>= 1) { CE_SHFL(e0, i0, k, j); CE_SHFL(e1, i1, k, j); }
    }

    u64* pg = pair_g + b * (NIN + 1);
    {
        unsigned ro0 = (unsigned)(e0 & 0xFFFFFFFFull) * (MOUT * 4);
        unsigned ro1 = (unsigned)(e1 & 0xFFFFFFFFull) * (MOUT * 4);
        pg[i0] = ((u64)ro0 << 32) | (unsigned)(e0 >> 32);
        pg[i1] = ((u64)ro1 << 32) | (unsigned)(e1 >> 32);
    }
    if (tid == 0) pg[NIN] = ((u64)0 << 32) | __float_as_uint(MAX_SPIKE);
}

// ---------------- kernel 2: per-column prefix snapshots --------------------
// One lane per column: exact sequential f32 cumsum over the full sorted row
// (identical op order to the reference); stores (wcum, wicum) at n = 128*s,
// s = 1..7. Latency-bound at 1 wave/SIMD -> CH=32 double-buffered prefetch.
__global__ __launch_bounds__(256) void snn_snap_kernel(const float* __restrict__ w,
                                                       const u64* __restrict__ pair_g,
                                                       float2* __restrict__ snap_g) {
    #pragma clang fp contract(off)
    __shared__ u64 pr[NIN];
    const int tid = threadIdx.x;
    const int b   = blockIdx.x >> 1;
    const int col = ((blockIdx.x & 1) << 8) + tid;
    const unsigned mo4 = (unsigned)col * 4u;

    const u64* __restrict__ pg = pair_g + b * (NIN + 1);
    for (int i = tid; i < NIN; i += 256) pr[i] = pg[i];
    __syncthreads();

    const char* wb = (const char*)w;
    float wcum = 0.0f, wicum = 0.0f;
    float wA[SCH], wB[SCH], xA[SCH], xB[SCH];

#define SLOAD(WR, XR, base_) { const int bb_ = (base_); _Pragma("unroll") \
    for (int u = 0; u < SCH; ++u) { \
        u64 p = pr[bb_ + u]; \
        XR[u] = __uint_as_float((unsigned)p); \
        WR[u] = *(const float*)(wb + ((unsigned)(p >> 32) + mo4)); } }

#define SSUM(WR, XR) { _Pragma("unroll") \
    for (int u = 0; u < SCH; ++u) { \
        float ww = WR[u]; \
        wcum  = wcum + ww; \
        wicum = wicum + ww * XR[u]; } }   /* round mul, then add (np order) */

    SLOAD(wA, xA, 0);
    constexpr int NCH = NIN / SCH;   // 32 chunks; boundary every 4 (n = 128*s)
    for (int c = 0; c < NCH; c += 2) {
        SLOAD(wB, xB, (c + 1) * SCH);
        if (c > 0 && (c & 3) == 0) {
            int seg = c >> 2;        // 1..7; state = exact prefix of seg*128
            snap_g[(seg - 1) * TOTCOL + b * MOUT + col] = make_float2(wcum, wicum);
        }
        SSUM(wA, xA);
        if (c + 2 < NCH) SLOAD(wA, xA, (c + 2) * SCH);
        SSUM(wB, xB);
    }
#undef SLOAD
#undef SSUM
}

// ---------------- kernel 3: 8-segment scan from snapshots ------------------
// Each wave: load bit-exact snapshot, screen-scan ONLY its 128 elements.
// Zero prefix redundancy; 8 waves/SIMD; VGPR pinned <= 64 by launch_bounds.
__global__ __launch_bounds__(512, 8) void snn_scan_kernel(const float* __restrict__ w,
                                                          const u64* __restrict__ pair_g,
                                                          const float2* __restrict__ snap_g,
                                                          float* __restrict__ out) {
    #pragma clang fp contract(off)
    __shared__ u64 pr[NIN + 1];
    __shared__ float bestsh[NWAVE][CPB];

    const int tid  = threadIdx.x;
    const int b    = blockIdx.x >> 3;
    const int cg   = blockIdx.x & 7;
    const int wave = tid >> 6;
    const int lane = tid & 63;
    const int seg  = (wave + blockIdx.x) & (NWAVE - 1);   // straggler swizzle
    const int col  = cg * CPB + lane;
    const unsigned mo4 = (unsigned)col * 4u;

    const u64* __restrict__ pg = pair_g + b * (NIN + 1);
    for (int i = tid; i < NIN + 1; i += 512) pr[i] = pg[i];
    __syncthreads();

    float wcum = 0.0f, wicum = 0.0f;
    if (seg > 0) {
        float2 s = snap_g[(seg - 1) * TOTCOL + b * MOUT + col];
        wcum = s.x; wicum = s.y;
    }
    float best = MAX_SPIKE;
    const char* wb = (const char*)w;
    const int n0 = seg * SEGLEN;
    bool scr = (__any((int)(wcum >= 1.0f)) != 0);

    float wA[CH], wB[CH], xsA[CH], xsB[CH];

#define LOADC(WR, XR, base_) { const int bb_ = (base_); _Pragma("unroll") \
    for (int u = 0; u < CH; ++u) { \
        u64 p = pr[bb_ + u]; \
        XR[u] = __uint_as_float((unsigned)p); \
        WR[u] = *(const float*)(wb + ((unsigned)(p >> 32) + mo4)); } }

    // Cheap mode while ALL lanes have wcum < 1 (weights >= 0 -> monotone ->
    // reference emits MAX_SPIKE exactly; no candidate possible). The chunk
    // where any lane crosses is REPLAYED from a 2-register snapshot in screen
    // mode (identical add order => bit-exact). Screen skips only when the
    // exact path provably rejects (1-ulp margins); borderline lanes take the
    // exact IEEE-division reference path.
#define PROCESS(WR, XR, xnext_) { \
    if (!scr) { \
        float wc0 = wcum, wi0 = wicum; \
        _Pragma("unroll") \
        for (int u = 0; u < CH; ++u) { \
            float ww = WR[u]; \
            wcum  = wcum + ww; \
            wicum = wicum + ww * XR[u]; \
        } \
        if (__any((int)(wcum >= 1.0f))) { wcum = wc0; wicum = wi0; scr = true; } \
    } \
    if (scr) { \
        _Pragma("unroll") \
        for (int u = 0; u < CH; ++u) { \
            float ww = WR[u]; \
            float xv = XR[u]; \
            float xl = (u < CH - 1) ? XR[u + 1] : (xnext_); \
            wcum  = wcum + ww; \
            wicum = wicum + ww * xv; \
            float d = fmaxf(wcum - 1.0f, 1e-10f); /* 1e10 clip never binds: wcum<=~4.3 */ \
            bool pot = (wcum >= 1.0f) && (wicum >= (xv * d) * (1.0f - 8e-7f)) \
                                      && (wicum <= (xl * d) * (1.0f + 8e-7f)); \
            if (pot) { \
                float q = wicum / d;            /* IEEE f32 div (matches np) */ \
                float cand = (q < xv || q > xl) ? MAX_SPIKE : q; \
                best = fminf(best, cand); \
            } \
        } \
    } }

    LOADC(wA, xsA, n0);
    constexpr int NCH2 = SEGLEN / CH;   // 16 (even)
    for (int c = 0; c < NCH2; c += 2) {
        LOADC(wB, xsB, n0 + (c + 1) * CH);
        PROCESS(wA, xsA, xsB[0]);
        const bool more = (c + 2 < NCH2);
        if (more) LOADC(wA, xsA, n0 + (c + 2) * CH);
        float xnB = more ? xsA[0] : __uint_as_float((unsigned)pr[n0 + SEGLEN]);
        PROCESS(wB, xsB, xnB);
    }
#undef PROCESS
#undef LOADC

    bestsh[wave][lane] = best;
    __syncthreads();
    if (tid < CPB) {
        float r0 = fminf(fminf(fminf(bestsh[0][tid], bestsh[1][tid]),
                               fminf(bestsh[2][tid], bestsh[3][tid])),
                         fminf(fminf(bestsh[4][tid], bestsh[5][tid]),
                               fminf(bestsh[6][tid], bestsh[7][tid])));
        out[b * MOUT + cg * CPB + tid] = r0;
    }
}

// ---------------- fallback: fused kernel (if ws too small) -----------------
__global__ __launch_bounds__(256) void snn_fc_fused(const float* __restrict__ x,
                                                    const float* __restrict__ w,
                                                    float* __restrict__ out) {
    #pragma clang fp contract(off)
    __shared__ u64 keys[NIN];
    __shared__ float xs[NIN + 1];
    __shared__ int   roff[NIN];
    __shared__ float bestsh[4][CPB];

    const int tid  = threadIdx.x;
    const int b    = blockIdx.x >> 3;
    const int cg   = blockIdx.x & 7;
    const int wave = tid >> 6;
    const int lane = tid & 63;
    const int mo   = cg * CPB + lane;

    for (int i = tid; i < NIN; i += 256) {
        unsigned int bits = __float_as_uint(x[b * NIN + i]);
        keys[i] = ((u64)bits << 32) | (unsigned int)i;
    }
    __syncthreads();
    for (int k = 2; k <= NIN; k <<= 1)
        for (int j = k >> 1; j > 0; j >>= 1) {
            #pragma unroll
            for (int r = 0; r < NIN / 256; ++r) {
                int i = tid + r * 256, ixj = i ^ j;
                if (ixj > i) {
                    u64 a = keys[i], c2 = keys[ixj];
                    bool asc = ((i & k) == 0);
                    if ((a > c2) == asc) { keys[i] = c2; keys[ixj] = a; }
                }
            }
            __syncthreads();
        }
    for (int i = tid; i < NIN; i += 256) {
        u64 kk = keys[i];
        xs[i]   = __uint_as_float((unsigned int)(kk >> 32));
        roff[i] = (int)(kk & 0xFFFFFFFFull) * MOUT;
    }
    if (tid == 0) xs[NIN] = MAX_SPIKE;
    __syncthreads();

    const float* __restrict__ wcol = w + mo;
    float wcum = 0.0f, wicum = 0.0f, best = MAX_SPIKE;

    for (int n = 0; n < wave * 256; ++n) {
        float ww = wcol[roff[n]];
        wcum = wcum + ww;
        wicum = wicum + ww * xs[n];
    }
    const int n0 = wave * 256;
    float xprev = xs[n0];
    for (int n = n0; n < n0 + 256; ++n) {
        float ww = wcol[roff[n]];
        float xv = xprev, xl = xs[n + 1];
        wcum = wcum + ww;
        wicum = wicum + ww * xv;
        float d = fminf(fmaxf(wcum - 1.0f, 1e-10f), 1e10f);
        float q = wicum / d;
        float cand = (wcum < 1.0f || q < xv || q > xl) ? MAX_SPIKE : q;
        best = fminf(best, cand);
        xprev = xl;
    }
    bestsh[wave][lane] = best;
    __syncthreads();
    if (tid < CPB) {
        float r0 = fminf(fminf(bestsh[0][tid], bestsh[1][tid]),
                         fminf(bestsh[2][tid], bestsh[3][tid]));
        out[b * MOUT + cg * CPB + tid] = r0;
    }
}

extern "C" void kernel_launch(void* const* d_in, const int* in_sizes, int n_in,
                              void* d_out, int out_size, void* d_ws, size_t ws_size,
                              hipStream_t stream) {
    (void)in_sizes; (void)n_in; (void)out_size;
    const float* x = (const float*)d_in[0];
    const float* w = (const float*)d_in[1];
    float* out = (float*)d_out;

    const size_t pair_bytes = (size_t)BATCH * (NIN + 1) * sizeof(u64);   // ~1.05 MB
    const size_t snap_bytes = (size_t)(NWAVE - 1) * TOTCOL * sizeof(float2); // ~3.67 MB

    if (ws_size >= pair_bytes + snap_bytes) {
        u64*    pair_g = (u64*)d_ws;
        float2* snap_g = (float2*)((char*)d_ws + pair_bytes);
        hipLaunchKernelGGL(snn_sort_kernel, dim3(BATCH), dim3(ST), 0, stream,
                           x, pair_g);
        hipLaunchKernelGGL(snn_snap_kernel, dim3(BATCH * 2), dim3(256), 0, stream,
                           w, pair_g, snap_g);
        hipLaunchKernelGGL(snn_scan_kernel, dim3(BATCH * (MOUT / CPB)), dim3(512),
                           0, stream, w, pair_g, snap_g, out);
    } else {
        hipLaunchKernelGGL(snn_fc_fused, dim3(BATCH * (MOUT / CPB)), dim3(256),
                           0, stream, x, w, out);
    }
}

// Round 9
// 63.324 us; speedup vs baseline: 1.5242x; 1.5242x over previous
//
#include <hip/hip_runtime.h>

#define MAX_SPIKE 100000.0f

constexpr int BATCH  = 128;
constexpr int NIN    = 1024;
constexpr int MOUT   = 512;
constexpr int NWAVE  = 2;             // n-segments per block
constexpr int SEGLEN = NIN / NWAVE;   // 512
constexpr int T      = 128;           // 2 waves per block
constexpr int CPB    = 64;            // columns per block (one per lane)
constexpr int CH     = 8;             // chunk
constexpr int ST     = 512;           // sort threads (8 waves)
constexpr int XSROW  = 1028;          // padded xs row stride (16B-aligned rows)

typedef unsigned long long u64;

// ---------------- kernel 1: per-row stable argsort (hybrid bitonic) --------
// j<=32 stages: __shfl_xor (no barriers). j==64: intra-thread. j>=128: LDS.
__global__ __launch_bounds__(ST) void snn_sort_kernel(const float* __restrict__ x,
                                                      float* __restrict__ xs_g,
                                                      int* __restrict__ ro_g) {
    __shared__ u64 keys[NIN];
    const int tid = threadIdx.x;
    const int b   = blockIdx.x;
    const int wv  = tid >> 6;
    const int l   = tid & 63;
    const int i0  = wv * 128 + l;     // bit6 == 0 always
    const int i1  = i0 + 64;

    // key = (float_bits << 32) | index: x >= 0 so uint order == float order;
    // index low bits make keys distinct -> deterministic == stable argsort.
    u64 e0 = ((u64)__float_as_uint(x[b * NIN + i0]) << 32) | (unsigned)i0;
    u64 e1 = ((u64)__float_as_uint(x[b * NIN + i1]) << 32) | (unsigned)i1;

    auto CE_SHFL = [&](u64& e, int idx, int k, int j) {
        u64 p = __shfl_xor(e, j, 64);
        bool lower   = ((l & j) == 0);
        bool asc     = ((idx & k) == 0);
        bool takeMin = (lower == asc);
        bool pLess   = (p < e);
        e = (pLess == takeMin) ? p : e;
    };
    auto CE_J64 = [&](int k) {
        bool asc = ((i0 & k) == 0);
        bool sw  = asc ? (e0 > e1) : (e0 < e1);
        if (sw) { u64 t = e0; e0 = e1; e1 = t; }
    };

    for (int k = 2; k <= 64; k <<= 1)
        for (int j = k >> 1; j >= 1; j >>= 1) { CE_SHFL(e0, i0, k, j); CE_SHFL(e1, i1, k, j); }
    CE_J64(128);
    for (int j = 32; j >= 1; j >>= 1) { CE_SHFL(e0, i0, 128, j); CE_SHFL(e1, i1, 128, j); }

    for (int k = 256; k <= NIN; k <<= 1) {
        keys[i0] = e0; keys[i1] = e1;
        __syncthreads();
        for (int j = k >> 1; j >= 128; j >>= 1) {
            int idx  = ((tid & ~(j - 1)) << 1) | (tid & (j - 1));
            int part = idx | j;
            u64 a = keys[idx], c = keys[part];
            bool asc = ((idx & k) == 0);
            if (asc ? (a > c) : (a < c)) { keys[idx] = c; keys[part] = a; }
            __syncthreads();
        }
        e0 = keys[i0]; e1 = keys[i1];
        CE_J64(k);
        for (int j = 32; j >= 1; j >>= 1) { CE_SHFL(e0, i0, k, j); CE_SHFL(e1, i1, k, j); }
    }

    xs_g[b * XSROW + i0] = __uint_as_float((unsigned)(e0 >> 32));
    xs_g[b * XSROW + i1] = __uint_as_float((unsigned)(e1 >> 32));
    ro_g[b * NIN + i0] = (int)(unsigned)(e0 & 0xFFFFFFFFull) * (MOUT * 4);  // byte off
    ro_g[b * NIN + i1] = (int)(unsigned)(e1 & 0xFFFFFFFFull) * (MOUT * 4);
    if (tid == 0) xs_g[b * XSROW + NIN] = MAX_SPIKE;
}

// ---------------- kernel 2: 2-segment scan, fma-screened division ----------
// NW2: 1.5x visit redundancy (vs NW4 2.5x / NW8 4.5x); bulk b128 LDS reads
// (float4 xs / int4 ro) cut ds issue 4x; screen via fmaf sign tests.
__global__ __launch_bounds__(T) void snn_scan_kernel(const float* __restrict__ w,
                                                     const float* __restrict__ xs_g,
                                                     const int* __restrict__ ro_g,
                                                     float* __restrict__ out) {
    // Cumsums + exact path must match numpy f32: no implicit FMA contraction.
    // (explicit fmaf below is only in the CONSERVATIVE screen, margin-covered)
    #pragma clang fp contract(off)

    __shared__ float4 xs4[NIN / 4 + 2];   // [256].x = MAX_SPIKE sentinel
    __shared__ int4   ro4[NIN / 4];
    __shared__ float  bestsh[NWAVE][CPB];

    const int tid  = threadIdx.x;
    const int b    = blockIdx.x >> 3;
    const int cg   = blockIdx.x & 7;
    const int wave = tid >> 6;
    const int lane = tid & 63;
    const int seg  = (wave + blockIdx.x) & (NWAVE - 1);   // straggler swizzle
    const unsigned mo4 = (unsigned)(cg * CPB + lane) * 4u;

    {
        const float4* __restrict__ xsrc = (const float4*)(xs_g + (size_t)b * XSROW);
        for (int i = tid; i < NIN / 4 + 1; i += T) xs4[i] = xsrc[i];
        const int4* __restrict__ rsrc = (const int4*)(ro_g + (size_t)b * NIN);
        for (int i = tid; i < NIN / 4; i += T) ro4[i] = rsrc[i];
    }
    __syncthreads();

    const char* wb = (const char*)w;
    float wcum = 0.0f, wicum = 0.0f, best = MAX_SPIKE;
    float XA[CH], XB[CH], WA[CH], WB[CH];

// read xs chunk (2x ds_read_b128) + issue 8 saddr-form weight loads
#define RDIS(X, W, c_) { const int cc_ = (c_); \
    float4 a0_ = xs4[cc_ * 2], a1_ = xs4[cc_ * 2 + 1]; \
    X[0] = a0_.x; X[1] = a0_.y; X[2] = a0_.z; X[3] = a0_.w; \
    X[4] = a1_.x; X[5] = a1_.y; X[6] = a1_.z; X[7] = a1_.w; \
    int4 r0_ = ro4[cc_ * 2], r1_ = ro4[cc_ * 2 + 1]; \
    W[0] = *(const float*)(wb + ((unsigned)r0_.x + mo4)); \
    W[1] = *(const float*)(wb + ((unsigned)r0_.y + mo4)); \
    W[2] = *(const float*)(wb + ((unsigned)r0_.z + mo4)); \
    W[3] = *(const float*)(wb + ((unsigned)r0_.w + mo4)); \
    W[4] = *(const float*)(wb + ((unsigned)r1_.x + mo4)); \
    W[5] = *(const float*)(wb + ((unsigned)r1_.y + mo4)); \
    W[6] = *(const float*)(wb + ((unsigned)r1_.z + mo4)); \
    W[7] = *(const float*)(wb + ((unsigned)r1_.w + mo4)); }

#define CHEAP8(X, W) { _Pragma("unroll") \
    for (int u = 0; u < CH; ++u) { \
        float ww = W[u]; \
        wcum  = wcum + ww; \
        wicum = wicum + ww * X[u]; } }   /* round mul, then add (np order) */

    const int s0   = seg * (SEGLEN / CH);   // 0 or 64
    const int cend = s0 + SEGLEN / CH;      // 64 or 128

    // ---- phase 1: exact sequential prefix over [0, seg*SEGLEN); no screens.
    if (s0 > 0) {
        RDIS(XA, WA, 0);
        for (int c = 0; c < s0; c += 2) {
            RDIS(XB, WB, c + 1);
            CHEAP8(XA, WA);
            if (c + 2 < s0) RDIS(XA, WA, c + 2);
            CHEAP8(XB, WB);
        }
    }

    // ---- phase 2: candidate scan on own segment.
    // Cheap mode while ALL lanes have wcum < 1 (weights >= 0 -> monotone ->
    // reference emits MAX_SPIKE exactly; no candidate). The crossing chunk is
    // REPLAYED from a 2-register snapshot (identical add order => bit-exact).
    // Screen: skip only when exact path PROVABLY rejects. q = RN(wi/d), so
    //   q < xv guaranteed if  xv*d - wi >  wi*2^-24  -> lo >  thr
    //   q > xl guaranteed if  wi - xl*d >  wi*2^-24  -> hi < -thr
    // with thr = wi*2.4e-7 (~4 ulp, conservative; fmaf single-rounding).
    // Borderline lanes fall into the exact IEEE-division reference path.
    bool scr = (__any((int)(wcum >= 1.0f)) != 0);

#define PROC(X, W, XL8) { \
    if (!scr) { \
        float wc0 = wcum, wi0 = wicum; \
        CHEAP8(X, W); \
        if (__any((int)(wcum >= 1.0f))) { wcum = wc0; wicum = wi0; scr = true; } \
    } \
    if (scr) { \
        _Pragma("unroll") \
        for (int u = 0; u < CH; ++u) { \
            float ww = W[u]; \
            float xv = X[u]; \
            float xl = (u < CH - 1) ? X[u + 1] : (XL8); \
            wcum  = wcum + ww; \
            wicum = wicum + ww * xv; \
            float d   = fmaxf(wcum - 1.0f, 1e-10f); /* 1e10 clip never binds: wcum<=~5 */ \
            float thr = wicum * 2.4e-7f; \
            float lo  = fmaf(xv, d, -wicum); \
            float hi  = fmaf(xl, d, -wicum); \
            bool pot = (wcum >= 1.0f) && (lo <= thr) && (hi >= -thr); \
            if (pot) { \
                float q = wicum / d;            /* IEEE f32 div (matches np) */ \
                float cand = (q < xv || q > xl) ? MAX_SPIKE : q; \
                best = fminf(best, cand); \
            } \
        } \
    } }

    RDIS(XA, WA, s0);
    for (int c = s0; c < cend; c += 2) {
        RDIS(XB, WB, c + 1);
        PROC(XA, WA, XB[0]);
        const bool more = (c + 2 < cend);
        if (more) RDIS(XA, WA, c + 2);
        float xlB = more ? XA[0] : xs4[(c + 2) * 2].x;  // xs[n0+SEGLEN] sentinel-safe
        PROC(XB, WB, xlB);
    }
#undef PROC
#undef CHEAP8
#undef RDIS

    bestsh[wave][lane] = best;
    __syncthreads();
    if (tid < CPB)
        out[b * MOUT + cg * CPB + tid] = fminf(bestsh[0][tid], bestsh[1][tid]);
}

// ---------------- fallback: fused kernel (if ws too small) -----------------
__global__ __launch_bounds__(256) void snn_fc_fused(const float* __restrict__ x,
                                                    const float* __restrict__ w,
                                                    float* __restrict__ out) {
    #pragma clang fp contract(off)
    __shared__ u64 keys[NIN];
    __shared__ float xs[NIN + 1];
    __shared__ int   roff[NIN];
    __shared__ float bestsh[4][CPB];

    const int tid  = threadIdx.x;
    const int b    = blockIdx.x >> 3;
    const int cg   = blockIdx.x & 7;
    const int wave = tid >> 6;
    const int lane = tid & 63;
    const int mo   = cg * CPB + lane;

    for (int i = tid; i < NIN; i += 256) {
        unsigned int bits = __float_as_uint(x[b * NIN + i]);
        keys[i] = ((u64)bits << 32) | (unsigned int)i;
    }
    __syncthreads();
    for (int k = 2; k <= NIN; k <<= 1)
        for (int j = k >> 1; j > 0; j >>= 1) {
            #pragma unroll
            for (int r = 0; r < NIN / 256; ++r) {
                int i = tid + r * 256, ixj = i ^ j;
                if (ixj > i) {
                    u64 a = keys[i], c2 = keys[ixj];
                    bool asc = ((i & k) == 0);
                    if ((a > c2) == asc) { keys[i] = c2; keys[ixj] = a; }
                }
            }
            __syncthreads();
        }
    for (int i = tid; i < NIN; i += 256) {
        u64 kk = keys[i];
        xs[i]   = __uint_as_float((unsigned int)(kk >> 32));
        roff[i] = (int)(kk & 0xFFFFFFFFull) * MOUT;
    }
    if (tid == 0) xs[NIN] = MAX_SPIKE;
    __syncthreads();

    const float* __restrict__ wcol = w + mo;
    float wcum = 0.0f, wicum = 0.0f, best = MAX_SPIKE;

    for (int n = 0; n < wave * 256; ++n) {
        float ww = wcol[roff[n]];
        wcum = wcum + ww;
        wicum = wicum + ww * xs[n];
    }
    const int n0 = wave * 256;
    float xprev = xs[n0];
    for (int n = n0; n < n0 + 256; ++n) {
        float ww = wcol[roff[n]];
        float xv = xprev, xl = xs[n + 1];
        wcum = wcum + ww;
        wicum = wicum + ww * xv;
        float d = fminf(fmaxf(wcum - 1.0f, 1e-10f), 1e10f);
        float q = wicum / d;
        float cand = (wcum < 1.0f || q < xv || q > xl) ? MAX_SPIKE : q;
        best = fminf(best, cand);
        xprev = xl;
    }
    bestsh[wave][lane] = best;
    __syncthreads();
    if (tid < CPB) {
        float r0 = fminf(fminf(bestsh[0][tid], bestsh[1][tid]),
                         fminf(bestsh[2][tid], bestsh[3][tid]));
        out[b * MOUT + cg * CPB + tid] = r0;
    }
}

extern "C" void kernel_launch(void* const* d_in, const int* in_sizes, int n_in,
                              void* d_out, int out_size, void* d_ws, size_t ws_size,
                              hipStream_t stream) {
    (void)in_sizes; (void)n_in; (void)out_size;
    const float* x = (const float*)d_in[0];
    const float* w = (const float*)d_in[1];
    float* out = (float*)d_out;

    const size_t xs_bytes = (size_t)BATCH * XSROW * sizeof(float);  // 526336
    const size_t ro_bytes = (size_t)BATCH * NIN * sizeof(int);      // 524288

    if (ws_size >= xs_bytes + ro_bytes) {
        float* xs_g = (float*)d_ws;
        int*   ro_g = (int*)((char*)d_ws + xs_bytes);
        hipLaunchKernelGGL(snn_sort_kernel, dim3(BATCH), dim3(ST), 0, stream,
                           x, xs_g, ro_g);
        hipLaunchKernelGGL(snn_scan_kernel, dim3(BATCH * (MOUT / CPB)), dim3(T),
                           0, stream, w, xs_g, ro_g, out);
    } else {
        hipLaunchKernelGGL(snn_fc_fused, dim3(BATCH * (MOUT / CPB)), dim3(256),
                           0, stream, x, w, out);
    }
}